// Round 1
// baseline (690.589 us; speedup 1.0000x reference)
//
#include <hip/hip_runtime.h>

// Problem constants
#define NN 16
#define SS 16384
#define VV 256
#define TT ((long)NN * SS)   // 262144 tokens
#define NC 47                 // total codes
#define SUT_STRIDE 48         // padded row for suT [v][c]

static constexpr int CB_SIZES_H[10] = {3, 5, 5, 5, 5, 3, 7, 8, 3, 3};
static constexpr int CB_OFF_H[10]   = {0, 3, 8, 13, 18, 23, 26, 33, 41, 44};

// ---------------------------------------------------------------------------
// Precompute kernel: for each code gc (g = group, c = code-in-group):
//   suT[v][gc] = -2 * sum_i W1[16g+i, v] * e[i]        (score vector, transposed)
//   proj[gc][v] = sum_i e[i] * W2[v, i*10+g]           (output contribution)
//   biasv[gc]  = sum_i e[i]*(e[i] - 2*b1[16g+i])       (score bias)
// ---------------------------------------------------------------------------
__global__ __launch_bounds__(256) void vq_pre(
    const float* __restrict__ W1, const float* __restrict__ b1,
    const float* __restrict__ W2,
    const float* __restrict__ cb0, const float* __restrict__ cb1,
    const float* __restrict__ cb2, const float* __restrict__ cb3,
    const float* __restrict__ cb4, const float* __restrict__ cb5,
    const float* __restrict__ cb6, const float* __restrict__ cb7,
    const float* __restrict__ cb8, const float* __restrict__ cb9,
    float* __restrict__ suT, float* __restrict__ biasv,
    float* __restrict__ proj)
{
    const float* cbs[10] = {cb0, cb1, cb2, cb3, cb4, cb5, cb6, cb7, cb8, cb9};
    const int gc = blockIdx.x;           // 0..46
    int g = 0;
    #pragma unroll
    for (int gg = 1; gg < 10; gg++) if (gc >= CB_OFF_H[gg]) g = gg;
    const int c = gc - CB_OFF_H[g];
    const float* e = cbs[g] + c * 16;    // cb shape (1, k, 16)

    const int v = threadIdx.x;           // 0..255
    float su = 0.f, pj = 0.f;
    #pragma unroll
    for (int i = 0; i < 16; i++)
        su = fmaf(W1[(long)(16 * g + i) * VV + v], e[i], su);
    suT[v * SUT_STRIDE + gc] = -2.f * su;
    #pragma unroll
    for (int i = 0; i < 16; i++)
        pj = fmaf(e[i], W2[(long)v * 160 + i * 10 + g], pj);
    proj[gc * VV + v] = pj;

    if (v == 0) {
        float b = 0.f;
        #pragma unroll
        for (int i = 0; i < 16; i++)
            b += e[i] * (e[i] - 2.f * b1[16 * g + i]);
        biasv[gc] = b;
    }
}

// ---------------------------------------------------------------------------
// Main kernel: one thread per token for the score phase (su loads are
// wave-uniform -> scalar loads; 47 FMAs per x element). Then the wave
// cooperates per token for the output phase (lane covers 4 of 256 v).
// ---------------------------------------------------------------------------
__global__ __launch_bounds__(256) void vq_main(
    const float* __restrict__ x, const float* __restrict__ suT,
    const float* __restrict__ biasv, const float* __restrict__ proj,
    const float* __restrict__ b2, float* __restrict__ out0,
    float* __restrict__ out1, float* __restrict__ out2)
{
    const int lane = threadIdx.x & 63;
    const int wv   = threadIdx.x >> 6;
    const long tbase = (long)blockIdx.x * 256 + wv * 64;  // wave's 64 tokens
    const long t = tbase + lane;
    const float* xr = x + t * VV;

    // ---- Phase 1: scores + argmin (thread = token) ----
    float acc[NC];
    #pragma unroll
    for (int c = 0; c < NC; c++) acc[c] = biasv[c];

    #pragma unroll 1
    for (int v0 = 0; v0 < VV; v0 += 16) {
        float xx[16];
        #pragma unroll
        for (int j = 0; j < 4; j++) {
            const float4 q = *(const float4*)(xr + v0 + 4 * j);
            xx[4 * j + 0] = q.x; xx[4 * j + 1] = q.y;
            xx[4 * j + 2] = q.z; xx[4 * j + 3] = q.w;
        }
        #pragma unroll
        for (int v = 0; v < 16; v++) {
            const float* srow = suT + (v0 + v) * SUT_STRIDE;  // uniform address
            #pragma unroll
            for (int c = 0; c < NC; c++)
                acc[c] = fmaf(xx[v], srow[c], acc[c]);
        }
    }

    unsigned pk = 0;  // 10 x 3-bit argmin indices
    #pragma unroll
    for (int g = 0; g < 10; g++) {
        const int off = CB_OFF_H[g];
        const int k = CB_SIZES_H[g];
        float best = acc[off];
        int bi = 0;
        #pragma unroll
        for (int c = 1; c < 8; c++) {
            if (c < k) {
                const float vv = acc[off + c];
                if (vv < best) { best = vv; bi = c; }  // strict <: first-min like np
            }
        }
        pk |= (unsigned)bi << (3 * g);
    }

    // ---- Phase 2: gather proj rows, write out0 and out1/out2 ----
    const float4 b2v = *(const float4*)(b2 + lane * 4);
    #pragma unroll 1
    for (int tok = 0; tok < 64; tok++) {
        const unsigned pkt = (unsigned)__shfl((int)pk, tok);
        float4 o = b2v;
        #pragma unroll
        for (int g = 0; g < 10; g++) {
            const int cc = CB_OFF_H[g] + (int)((pkt >> (3 * g)) & 7u);
            const float4 p = *(const float4*)(proj + cc * VV + lane * 4);
            o.x += p.x; o.y += p.y; o.z += p.z; o.w += p.w;
        }
        const long tt = tbase + tok;
        const float4 xv = *(const float4*)(x + tt * VV + lane * 4);
        // out0 = (out - x) + x, matching reference rounding
        float4 s;
        s.x = (o.x - xv.x) + xv.x;
        s.y = (o.y - xv.y) + xv.y;
        s.z = (o.z - xv.z) + xv.z;
        s.w = (o.w - xv.w) + xv.w;
        *(float4*)(out0 + tt * VV + lane * 4) = s;

        const float dx = xv.x - o.x, dy = xv.y - o.y,
                    dz = xv.z - o.z, dw = xv.w - o.w;
        float pr = dx * dx + dy * dy + dz * dz + dw * dw;
        #pragma unroll
        for (int off = 32; off > 0; off >>= 1)
            pr += __shfl_xor(pr, off);
        if (lane == 0) { out1[tt] = pr; out2[tt] = pr; }
    }
}

// ---------------------------------------------------------------------------
extern "C" void kernel_launch(void* const* d_in, const int* in_sizes, int n_in,
                              void* d_out, int out_size, void* d_ws, size_t ws_size,
                              hipStream_t stream) {
    const float* x0 = (const float*)d_in[0];
    const float* W1 = (const float*)d_in[1];
    const float* b1 = (const float*)d_in[2];
    const float* W2 = (const float*)d_in[3];
    const float* b2 = (const float*)d_in[4];
    const float* cb[10];
    for (int i = 0; i < 10; i++) cb[i] = (const float*)d_in[5 + i];

    float* ws    = (float*)d_ws;
    float* suT   = ws;                       // 256*48 = 12288 floats
    float* biasv = ws + 12288;               // 48 floats
    float* proj  = ws + 12288 + 48;          // 47*256 floats (16B-aligned: 49344 B)

    float* out0 = (float*)d_out;
    float* out1 = out0 + (long)NN * SS * VV; // 67108864
    float* out2 = out1 + (long)NN * SS;      // +262144

    vq_pre<<<NC, 256, 0, stream>>>(W1, b1, W2,
        cb[0], cb[1], cb[2], cb[3], cb[4], cb[5], cb[6], cb[7], cb[8], cb[9],
        suT, biasv, proj);

    vq_main<<<(int)(TT / 256), 256, 0, stream>>>(
        x0, suT, biasv, proj, b2, out0, out1, out2);
}

// Round 2
// 657.564 us; speedup vs baseline: 1.0502x; 1.0502x over previous
//
#include <hip/hip_runtime.h>

#define NN 16
#define SS 16384
#define VV 256
#define TT ((long)NN * SS)   // 262144 tokens
#define NC 47                // total codes
#define SUT_STRIDE 48        // padded row for suT [v][c]

static constexpr int CB_SIZES_H[10] = {3, 5, 5, 5, 5, 3, 7, 8, 3, 3};
static constexpr int CB_OFF_H[10]   = {0, 3, 8, 13, 18, 23, 26, 33, 41, 44};

typedef float v4f __attribute__((ext_vector_type(4)));

// ---------------------------------------------------------------------------
// Precompute: suT[v][gc] = -2*W1_g^T e_c ; proj[gc][v] = W2[:,i*10+g]·e ;
// biasv[gc] = e·e - 2 b1_g·e
// ---------------------------------------------------------------------------
__global__ __launch_bounds__(256) void vq_pre(
    const float* __restrict__ W1, const float* __restrict__ b1,
    const float* __restrict__ W2,
    const float* __restrict__ cb0, const float* __restrict__ cb1,
    const float* __restrict__ cb2, const float* __restrict__ cb3,
    const float* __restrict__ cb4, const float* __restrict__ cb5,
    const float* __restrict__ cb6, const float* __restrict__ cb7,
    const float* __restrict__ cb8, const float* __restrict__ cb9,
    float* __restrict__ suT, float* __restrict__ biasv,
    float* __restrict__ proj)
{
    const float* cbs[10] = {cb0, cb1, cb2, cb3, cb4, cb5, cb6, cb7, cb8, cb9};
    const int gc = blockIdx.x;           // 0..46
    int g = 0;
    #pragma unroll
    for (int gg = 1; gg < 10; gg++) if (gc >= CB_OFF_H[gg]) g = gg;
    const int c = gc - CB_OFF_H[g];
    const float* e = cbs[g] + c * 16;

    const int v = threadIdx.x;           // 0..255
    float su = 0.f, pj = 0.f;
    #pragma unroll
    for (int i = 0; i < 16; i++)
        su = fmaf(W1[(long)(16 * g + i) * VV + v], e[i], su);
    suT[v * SUT_STRIDE + gc] = -2.f * su;
    #pragma unroll
    for (int i = 0; i < 16; i++)
        pj = fmaf(e[i], W2[(long)v * 160 + i * 10 + g], pj);
    proj[gc * VV + v] = pj;

    if (v == 0) {
        float b = 0.f;
        #pragma unroll
        for (int i = 0; i < 16; i++)
            b += e[i] * (e[i] - 2.f * b1[16 * g + i]);
        biasv[gc] = b;
    }
}

// ---------------------------------------------------------------------------
// Kernel A: scores + argmin. Block = 256 tokens, thread-per-token.
// x staged through a transposed LDS tile so global loads are (64B-segment)
// coalesced and compute reads are bank-conflict-free. suT reads are
// wave-uniform -> scalar loads.
// ---------------------------------------------------------------------------
__global__ __launch_bounds__(256) void vq_score(
    const float* __restrict__ x, const float* __restrict__ suT,
    const float* __restrict__ biasv, unsigned* __restrict__ pk)
{
    __shared__ float xt[16][257];
    const int tid = threadIdx.x;
    const long t0 = (long)blockIdx.x * 256;

    float acc[NC];
    #pragma unroll
    for (int c = 0; c < NC; c++) acc[c] = biasv[c];

    const int q  = tid & 3;      // which float4 of the 16-v chunk
    const int t4 = tid >> 2;     // 0..63 base token within tile

    #pragma unroll 1
    for (int v0 = 0; v0 < VV; v0 += 16) {
        __syncthreads();   // previous chunk's reads done before overwrite
        #pragma unroll
        for (int j = 0; j < 4; j++) {
            const int tt = t4 + 64 * j;
            const float4 qv = *(const float4*)(x + (t0 + tt) * VV + v0 + 4 * q);
            xt[4 * q + 0][tt] = qv.x;
            xt[4 * q + 1][tt] = qv.y;
            xt[4 * q + 2][tt] = qv.z;
            xt[4 * q + 3][tt] = qv.w;
        }
        __syncthreads();
        #pragma unroll
        for (int v = 0; v < 16; v++) {
            const float xv = xt[v][tid];
            const float* srow = suT + (v0 + v) * SUT_STRIDE;  // wave-uniform
            #pragma unroll
            for (int c = 0; c < NC; c++)
                acc[c] = fmaf(xv, srow[c], acc[c]);
        }
    }

    unsigned p = 0;  // 10 x 3-bit argmin indices
    #pragma unroll
    for (int g = 0; g < 10; g++) {
        const int off = CB_OFF_H[g];
        const int k = CB_SIZES_H[g];
        float best = acc[off];
        int bi = 0;
        #pragma unroll
        for (int c = 1; c < 8; c++) {
            if (c < k) {
                const float vv = acc[off + c];
                if (vv < best) { best = vv; bi = c; }  // strict <: np first-min
            }
        }
        p |= (unsigned)bi << (3 * g);
    }
    pk[t0 + tid] = p;
}

// ---------------------------------------------------------------------------
// Kernel B: streaming output. proj in LDS; wave handles 64 tokens, lane
// covers 4 consecutive v. Low VGPR -> high occupancy -> HBM-bound.
// ---------------------------------------------------------------------------
__global__ __launch_bounds__(512) void vq_out(
    const float* __restrict__ x, const unsigned* __restrict__ pk,
    const float* __restrict__ proj, const float* __restrict__ b2,
    float* __restrict__ out0, float* __restrict__ out1,
    float* __restrict__ out2)
{
    __shared__ v4f pl[NC * 64];  // 47 KB: proj as [code][64 x float4]
    const int tid = threadIdx.x;
    for (int i = tid; i < NC * 64; i += 512)
        pl[i] = ((const v4f*)proj)[i];
    __syncthreads();

    const int lane = tid & 63;
    const int w    = tid >> 6;
    const long tbase = (long)blockIdx.x * 512 + (long)w * 64;
    const unsigned pkme = pk[tbase + lane];
    const v4f b2v = ((const v4f*)b2)[lane];

    #pragma unroll 1
    for (int tok = 0; tok < 64; tok++) {
        const unsigned pkt = (unsigned)__shfl((int)pkme, tok);
        v4f o = b2v;
        #pragma unroll
        for (int g = 0; g < 10; g++) {
            const int cc = CB_OFF_H[g] + (int)((pkt >> (3 * g)) & 7u);
            o += pl[cc * 64 + lane];
        }
        const long t = tbase + tok;
        const v4f xv = ((const v4f*)(x + t * VV))[lane];
        v4f s = (o - xv) + xv;   // match reference rounding for out0
        __builtin_nontemporal_store(s, (v4f*)(out0 + t * VV) + lane);

        const v4f d = xv - o;
        float pr = d.x * d.x + d.y * d.y + d.z * d.z + d.w * d.w;
        #pragma unroll
        for (int off = 32; off > 0; off >>= 1)
            pr += __shfl_xor(pr, off);
        if (lane == 0)  out1[t] = pr;
        if (lane == 32) out2[t] = pr;
    }
}

// ---------------------------------------------------------------------------
extern "C" void kernel_launch(void* const* d_in, const int* in_sizes, int n_in,
                              void* d_out, int out_size, void* d_ws, size_t ws_size,
                              hipStream_t stream) {
    const float* x0 = (const float*)d_in[0];
    const float* W1 = (const float*)d_in[1];
    const float* b1 = (const float*)d_in[2];
    const float* W2 = (const float*)d_in[3];
    const float* b2 = (const float*)d_in[4];
    const float* cb[10];
    for (int i = 0; i < 10; i++) cb[i] = (const float*)d_in[5 + i];

    float* ws    = (float*)d_ws;
    float* suT   = ws;                        // 256*48 = 12288 floats
    float* biasv = ws + 12288;                // 48 floats
    float* proj  = ws + 12288 + 48;           // 47*256 = 12032 floats
    unsigned* pk = (unsigned*)(ws + 24368);   // 262144 uints (byte off 97472, 16B aligned)

    float* out0 = (float*)d_out;
    float* out1 = out0 + (long)NN * SS * VV;  // 67108864
    float* out2 = out1 + (long)NN * SS;       // +262144

    vq_pre<<<NC, 256, 0, stream>>>(W1, b1, W2,
        cb[0], cb[1], cb[2], cb[3], cb[4], cb[5], cb[6], cb[7], cb[8], cb[9],
        suT, biasv, proj);

    vq_score<<<(int)(TT / 256), 256, 0, stream>>>(x0, suT, biasv, pk);

    vq_out<<<(int)(TT / 512), 512, 0, stream>>>(
        x0, pk, proj, b2, out0, out1, out2);
}